// Round 1
// baseline (813.671 us; speedup 1.0000x reference)
//
#include <hip/hip_runtime.h>

// Problem constants (fixed by the reference)
#define BB   2
#define HH   32
#define HKV  8
#define GQ   4      // H / Hkv
#define TT   4096
#define DD   64
#define FF   64
#define WW   64
#define NBLK 64     // T / W
#define PADW 68     // row stride in LDS floats (64 + 4 pad, keeps 16B align)

#define INV_D4TH   0.35355339059327373f   // 1 / 64^0.25
#define INV_SQRT_F 0.125f                 // 1 / sqrt(64)
#define SQN_SCALE  0.0625f                // 0.5 / sqrt(64)
#define INV_SQRT_D 0.125f                 // 1 / sqrt(64)

// ---------------------------------------------------------------------------
// Kernel 1: per (b,kv,n) block -> S_blk[F][D] = phi_k^T @ v, z_blk[F]
// grid = BB*HKV*NBLK blocks of 256 threads
// ---------------------------------------------------------------------------
__global__ __launch_bounds__(256) void k_phase1(const float* __restrict__ kg,
                                                const float* __restrict__ vg,
                                                const float* __restrict__ pg,
                                                float* __restrict__ S,
                                                float* __restrict__ z) {
    __shared__ __align__(16) float proj_s[FF][PADW];
    __shared__ __align__(16) float x_s[WW][PADW];
    __shared__ __align__(16) float phi_s[WW][PADW];
    __shared__ __align__(16) float v_s[WW][PADW];

    const int tid = threadIdx.x;
    const int bid = blockIdx.x;            // = (b*HKV + kv)*NBLK + n
    const int n   = bid % NBLK;
    const int kvb = bid / NBLK;            // b*HKV + kv
    (void)n;

    const size_t kbase = ((size_t)kvb * TT + (size_t)(bid % NBLK) * WW) * DD;
    const float4* k4 = (const float4*)(kg + kbase);
    const float4* v4 = (const float4*)(vg + kbase);
    const float4* p4 = (const float4*)pg;

#pragma unroll
    for (int j = 0; j < 4; ++j) {
        int i4 = tid + j * 256;            // 0..1023 (1024 float4 = 4096 floats)
        int row = i4 >> 4;
        int c4  = (i4 & 15) * 4;
        *(float4*)&x_s[row][c4]    = k4[i4];
        *(float4*)&v_s[row][c4]    = v4[i4];
        *(float4*)&proj_s[row][c4] = p4[i4];
    }
    __syncthreads();

    const int r = tid >> 2;   // row / feature index
    const int c = tid & 3;    // quarter

    // cache k row in registers
    float4 xr[16];
#pragma unroll
    for (int i = 0; i < 16; ++i) xr[i] = *(const float4*)&x_s[r][i * 4];
    float sqn = 0.f;
#pragma unroll
    for (int i = 0; i < 16; ++i)
        sqn += xr[i].x * xr[i].x + xr[i].y * xr[i].y + xr[i].z * xr[i].z + xr[i].w * xr[i].w;
    sqn *= SQN_SCALE;

    // phi_k for 16 features
#pragma unroll 4
    for (int j = 0; j < 16; ++j) {
        int f = c * 16 + j;
        float p = 0.f;
#pragma unroll
        for (int i = 0; i < 16; ++i) {
            float4 pr = *(const float4*)&proj_s[f][i * 4];
            p += xr[i].x * pr.x + xr[i].y * pr.y + xr[i].z * pr.z + xr[i].w * pr.w;
        }
        p *= INV_D4TH;
        float lg = fminf(fmaxf(p - sqn, -20.f), 20.f);
        phi_s[r][f] = __expf(lg) * INV_SQRT_F;
    }
    __syncthreads();

    // S_blk[f][d] = sum_w phi[w][f] * v[w][d]; this thread: f = r, d in [c*16, c*16+16)
    float acc[16];
#pragma unroll
    for (int j = 0; j < 16; ++j) acc[j] = 0.f;
    for (int w = 0; w < WW; ++w) {
        float ph = phi_s[w][r];
#pragma unroll
        for (int j4 = 0; j4 < 4; ++j4) {
            float4 vv = *(const float4*)&v_s[w][c * 16 + j4 * 4];
            acc[j4 * 4 + 0] += ph * vv.x;
            acc[j4 * 4 + 1] += ph * vv.y;
            acc[j4 * 4 + 2] += ph * vv.z;
            acc[j4 * 4 + 3] += ph * vv.w;
        }
    }
    float* Sp = S + (size_t)bid * (FF * DD) + r * DD + c * 16;
#pragma unroll
    for (int j4 = 0; j4 < 4; ++j4) {
        float4 o;
        o.x = acc[j4 * 4 + 0]; o.y = acc[j4 * 4 + 1];
        o.z = acc[j4 * 4 + 2]; o.w = acc[j4 * 4 + 3];
        *(float4*)(Sp + j4 * 4) = o;
    }
    if (c == 0) {
        float zz = 0.f;
        for (int w = 0; w < WW; ++w) zz += phi_s[w][r];
        z[(size_t)bid * FF + r] = zz;
    }
}

// ---------------------------------------------------------------------------
// Kernel 2: in-place shifted prefix sum over blocks (delay 2): out[n]=sum_{m<=n-2}
// blocks 0..255: S (16 pairs * 16 chunks of 256 elems); blocks 256..259: z
// ---------------------------------------------------------------------------
__global__ __launch_bounds__(256) void k_scan(float* __restrict__ S,
                                              float* __restrict__ z) {
    const int tid = threadIdx.x;
    if (blockIdx.x < 256) {
        int pair  = blockIdx.x >> 4;           // 0..15 (b*HKV+kv)
        int chunk = blockIdx.x & 15;
        int elem  = chunk * 256 + tid;         // 0..4095 (f*64+d)
        size_t base = (size_t)pair * NBLK * FF * DD + elem;
        const size_t stride = FF * DD;
        float c0 = 0.f, c1 = 0.f;
        for (int n = 0; n < NBLK; ++n) {
            size_t idx = base + (size_t)n * stride;
            float val = S[idx];
            S[idx] = c0;
            c0 = c1;
            c1 += val;
        }
    } else {
        int i = (blockIdx.x - 256) * 256 + tid;  // 0..1023
        int pair = i >> 6;
        int f    = i & 63;
        size_t base = (size_t)pair * NBLK * FF + f;
        float c0 = 0.f, c1 = 0.f;
        for (int n = 0; n < NBLK; ++n) {
            size_t idx = base + (size_t)n * FF;
            float val = z[idx];
            z[idx] = c0;
            c0 = c1;
            c1 += val;
        }
    }
}

// ---------------------------------------------------------------------------
// Kernel 3: main. grid = BB*HH*NBLK blocks of 256 threads.
// thread = (r = query row 0..63, c = quarter 0..3)
// ---------------------------------------------------------------------------
__global__ __launch_bounds__(256) void k_main(const float* __restrict__ qg,
                                              const float* __restrict__ kg,
                                              const float* __restrict__ vg,
                                              const float* __restrict__ pg,
                                              const float* __restrict__ Sg,
                                              const float* __restrict__ zg,
                                              float* __restrict__ outg) {
    __shared__ __align__(16) float buf1[FF][PADW];      // proj, later S_used
    __shared__ __align__(16) float q_s[WW][PADW];
    __shared__ __align__(16) float phi_s[WW][PADW];
    __shared__ __align__(16) float k_s[2 * WW][PADW];
    __shared__ __align__(16) float v_s[2 * WW][PADW];
    __shared__ float z_s[FF];

    const int tid = threadIdx.x;
    const int bid = blockIdx.x;
    const int n = bid % NBLK;
    const int h = (bid / NBLK) % HH;
    const int b = bid / (NBLK * HH);
    const int kv = h / GQ;
    const int sblk = ((b * HKV + kv) * NBLK) + n;

    const size_t qbase  = ((size_t)(b * HH + h) * TT + (size_t)n * WW) * DD;
    const size_t kvbase = ((size_t)(b * HKV + kv) * TT + (size_t)n * WW) * DD;

    const float4* q4  = (const float4*)(qg + qbase);
    const float4* p4  = (const float4*)pg;
    const float4* kc4 = (const float4*)(kg + kvbase);
    const float4* vc4 = (const float4*)(vg + kvbase);
    const float4* kp4 = (const float4*)(kg + kvbase - (size_t)WW * DD); // valid iff n>0
    const float4* vp4 = (const float4*)(vg + kvbase - (size_t)WW * DD);

    // ---- load proj, q, k(prev|cur), v(prev|cur), z
#pragma unroll
    for (int j = 0; j < 4; ++j) {
        int i4 = tid + j * 256;
        int row = i4 >> 4;
        int c4  = (i4 & 15) * 4;
        *(float4*)&buf1[row][c4] = p4[i4];
        *(float4*)&q_s[row][c4]  = q4[i4];
        // current block -> rows 64..127
        *(float4*)&k_s[WW + row][c4] = kc4[i4];
        *(float4*)&v_s[WW + row][c4] = vc4[i4];
        // previous block -> rows 0..63 (zeros if n == 0)
        if (n > 0) {
            *(float4*)&k_s[row][c4] = kp4[i4];
            *(float4*)&v_s[row][c4] = vp4[i4];
        } else {
            float4 zf; zf.x = zf.y = zf.z = zf.w = 0.f;
            *(float4*)&k_s[row][c4] = zf;
            *(float4*)&v_s[row][c4] = zf;
        }
    }
    if (tid < FF) z_s[tid] = zg[(size_t)sblk * FF + tid];
    __syncthreads();

    const int r = tid >> 2;
    const int c = tid & 3;

    // cache q row in registers
    float4 xr[16];
#pragma unroll
    for (int i = 0; i < 16; ++i) xr[i] = *(const float4*)&q_s[r][i * 4];
    float sqn = 0.f;
#pragma unroll
    for (int i = 0; i < 16; ++i)
        sqn += xr[i].x * xr[i].x + xr[i].y * xr[i].y + xr[i].z * xr[i].z + xr[i].w * xr[i].w;
    sqn *= SQN_SCALE;

    // ---- phi_q (reads buf1 = proj)
#pragma unroll 4
    for (int j = 0; j < 16; ++j) {
        int f = c * 16 + j;
        float p = 0.f;
#pragma unroll
        for (int i = 0; i < 16; ++i) {
            float4 pr = *(const float4*)&buf1[f][i * 4];
            p += xr[i].x * pr.x + xr[i].y * pr.y + xr[i].z * pr.z + xr[i].w * pr.w;
        }
        p *= INV_D4TH;
        float lg = fminf(fmaxf(p - sqn, -20.f), 20.f);
        phi_s[r][f] = __expf(lg) * INV_SQRT_F;
    }
    __syncthreads();   // phi done; proj reads done -> buf1 reusable

    // ---- overwrite buf1 with S_used for this block (4096 floats)
    {
        const float4* S4 = (const float4*)(Sg + (size_t)sblk * FF * DD);
#pragma unroll
        for (int j = 0; j < 4; ++j) {
            int i4 = tid + j * 256;
            int row = i4 >> 4;
            int c4  = (i4 & 15) * 4;
            *(float4*)&buf1[row][c4] = S4[i4];
        }
    }

    // ---- local scores + exp (masked), a kept in registers
    float a_reg[32];
    float asum = 0.f;
#pragma unroll 4
    for (int i = 0; i < 32; ++i) {
        int x = c * 32 + i;
        float s = 0.f;
#pragma unroll
        for (int i4 = 0; i4 < 16; ++i4) {
            float4 kk = *(const float4*)&k_s[x][i4 * 4];
            s += xr[i4].x * kk.x + xr[i4].y * kk.y + xr[i4].z * kk.z + xr[i4].w * kk.w;
        }
        s *= INV_SQRT_D;
        bool valid = (x >= WW) ? ((x - WW) <= r) : (n > 0);
        float av = 0.f;
        if (valid) av = __expf(fminf(fmaxf(s, -30.f), 30.f));
        a_reg[i] = av;
        asum += av;
    }
    asum += __shfl_xor(asum, 1);
    asum += __shfl_xor(asum, 2);

    // ---- num_loc = a @ vv2 : chunked partials + 4-lane shuffle reduce
    float outv[16];
#pragma unroll 1
    for (int cc = 0; cc < 4; ++cc) {
        float part[16];
#pragma unroll
        for (int j = 0; j < 16; ++j) part[j] = 0.f;
        for (int i = 0; i < 32; ++i) {
            int x = c * 32 + i;
            float av = a_reg[i];
#pragma unroll
            for (int j4 = 0; j4 < 4; ++j4) {
                float4 vv = *(const float4*)&v_s[x][cc * 16 + j4 * 4];
                part[j4 * 4 + 0] += av * vv.x;
                part[j4 * 4 + 1] += av * vv.y;
                part[j4 * 4 + 2] += av * vv.z;
                part[j4 * 4 + 3] += av * vv.w;
            }
        }
#pragma unroll
        for (int j = 0; j < 16; ++j) {
            part[j] += __shfl_xor(part[j], 1);
            part[j] += __shfl_xor(part[j], 2);
        }
        if (cc == c) {
#pragma unroll
            for (int j = 0; j < 16; ++j) outv[j] = part[j];
        }
    }

    __syncthreads();   // buf1 now holds S_used for all threads

    // ---- num_lin = phi @ S_used, den_lin = phi @ z_used
    float lacc[16];
#pragma unroll
    for (int j = 0; j < 16; ++j) lacc[j] = 0.f;
    float dl = 0.f;
    for (int f = 0; f < FF; ++f) {
        float ph = phi_s[r][f];
        dl += ph * z_s[f];
#pragma unroll
        for (int j4 = 0; j4 < 4; ++j4) {
            float4 sv = *(const float4*)&buf1[f][c * 16 + j4 * 4];
            lacc[j4 * 4 + 0] += ph * sv.x;
            lacc[j4 * 4 + 1] += ph * sv.y;
            lacc[j4 * 4 + 2] += ph * sv.z;
            lacc[j4 * 4 + 3] += ph * sv.w;
        }
    }

    const float den = asum + dl + 1e-6f;
    const float inv = 1.0f / den;

    float* op = outg + ((size_t)(b * HH + h) * TT + (size_t)n * WW + r) * DD + c * 16;
#pragma unroll
    for (int j4 = 0; j4 < 4; ++j4) {
        float4 o;
        o.x = (outv[j4 * 4 + 0] + lacc[j4 * 4 + 0]) * inv;
        o.y = (outv[j4 * 4 + 1] + lacc[j4 * 4 + 1]) * inv;
        o.z = (outv[j4 * 4 + 2] + lacc[j4 * 4 + 2]) * inv;
        o.w = (outv[j4 * 4 + 3] + lacc[j4 * 4 + 3]) * inv;
        *(float4*)(op + j4 * 4) = o;
    }
}

// ---------------------------------------------------------------------------
extern "C" void kernel_launch(void* const* d_in, const int* in_sizes, int n_in,
                              void* d_out, int out_size, void* d_ws, size_t ws_size,
                              hipStream_t stream) {
    const float* q    = (const float*)d_in[0];
    const float* k    = (const float*)d_in[1];
    const float* v    = (const float*)d_in[2];
    const float* proj = (const float*)d_in[3];
    float* out = (float*)d_out;

    float* S = (float*)d_ws;                                   // [B*HKV*NB][F][D]
    float* z = S + (size_t)BB * HKV * NBLK * FF * DD;          // [B*HKV*NB][F]

    k_phase1<<<dim3(BB * HKV * NBLK), dim3(256), 0, stream>>>(k, v, proj, S, z);
    k_scan<<<dim3(260), dim3(256), 0, stream>>>(S, z);
    k_main<<<dim3(BB * HH * NBLK), dim3(256), 0, stream>>>(q, k, v, proj, S, z, out);
}

// Round 2
// 82.714 us; speedup vs baseline: 9.8372x; 9.8372x over previous
//
#include <hip/hip_runtime.h>

#define BB 2
#define HH 32
#define HKV 8
#define GQ 4
#define TT 4096
#define DD 64
#define FF 64
#define WW 64
#define NBLK 64

#define SCL 0.35355339059327373f  // 64^-0.25, folded into q and k

typedef __attribute__((ext_vector_type(8))) short short8;
typedef __attribute__((ext_vector_type(4))) float f32x4;

__device__ __forceinline__ unsigned short f2bf(float x) {
    union { float f; unsigned u; } v; v.f = x;
    unsigned r = v.u + 0x7fffu + ((v.u >> 16) & 1u);
    return (unsigned short)(r >> 16);
}
__device__ __forceinline__ unsigned pk2(float lo, float hi) {
    return (unsigned)f2bf(lo) | ((unsigned)f2bf(hi) << 16);
}
__device__ __forceinline__ f32x4 mfma16(short8 a, short8 b, f32x4 c) {
    return __builtin_amdgcn_mfma_f32_16x16x32_bf16(a, b, c, 0, 0, 0);
}
// Read an 8-bf16 A-frag from a swizzled LDS tile: row-major, row stride 2^lg2 bytes,
// swizzle byte ^= (row&7)<<4 (matches the staging writes below).
__device__ __forceinline__ short8 ldsfrag(const char* base, int row, int lg2, int off) {
    int b = (row << lg2) + off;
    b ^= (row & 7) << 4;
    return *(const short8*)(base + b);
}
// C-frag pair (tiles t0,t1 over 32 X-rows, col=lane&15) -> A/B-frag with
// k = X = (lane>>4)*8 + j, same col. Cross-group register exchange via shfl.
__device__ __forceinline__ short8 xform(f32x4 t0, f32x4 t1, int lane) {
    const int c = lane & 15, g = lane >> 4;
    unsigned p00 = pk2(t0[0], t0[1]), p01 = pk2(t0[2], t0[3]);
    unsigned p10 = pk2(t1[0], t1[1]), p11 = pk2(t1[2], t1[3]);
    int srcA = c + 32 * (g & 1);
    int srcB = srcA + 16;
    unsigned a00 = (unsigned)__shfl((int)p00, srcA);
    unsigned a01 = (unsigned)__shfl((int)p01, srcA);
    unsigned a10 = (unsigned)__shfl((int)p10, srcA);
    unsigned a11 = (unsigned)__shfl((int)p11, srcA);
    unsigned b00 = (unsigned)__shfl((int)p00, srcB);
    unsigned b01 = (unsigned)__shfl((int)p01, srcB);
    unsigned b10 = (unsigned)__shfl((int)p10, srcB);
    unsigned b11 = (unsigned)__shfl((int)p11, srcB);
    bool hi = (g & 2);
    union { unsigned u[4]; short8 s; } r;
    r.u[0] = hi ? a10 : a00;
    r.u[1] = hi ? a11 : a01;
    r.u[2] = hi ? b10 : b00;
    r.u[3] = hi ? b11 : b01;
    return r.s;
}

// ---------------------------------------------------------------------------
// Phase 1: per (b,kv,n): phi_k via MFMA, then S_blk^T[d][f] = (v^T · phi_k),
// z[f] = colsum(phi_k). 1024 blocks x 256 threads (4 waves, wave = 16 f's).
// ---------------------------------------------------------------------------
__global__ __launch_bounds__(256, 4) void k_phase1(const float* __restrict__ kg,
                                                   const float* __restrict__ vg,
                                                   const float* __restrict__ pg,
                                                   float* __restrict__ Sg,
                                                   float* __restrict__ zg) {
    __shared__ __align__(16) char kb_s[64 * 128];  // [key][64 bf16] swz, k*SCL
    __shared__ __align__(16) char vt_s[64 * 128];  // [d][64 keys bf16] swz
    __shared__ float sqn_s[64];

    const int tid = threadIdx.x;
    const int bid = blockIdx.x;                    // (b*HKV+kv)*64 + n
    const size_t base = (size_t)bid * (WW * DD);

    if (tid < 64) sqn_s[tid] = 0.f;
    __syncthreads();

    for (int j = 0; j < 4; ++j) {
        int i4 = tid + j * 256;        // 0..1023
        int key = i4 >> 4;
        int d0 = (i4 & 15) << 2;
        float4 fk = *(const float4*)(kg + base + (size_t)key * DD + d0);
        float s0 = fk.x * SCL, s1 = fk.y * SCL, s2 = fk.z * SCL, s3 = fk.w * SCL;
        int byte = (key << 7) + (d0 << 1); byte ^= (key & 7) << 4;
        *(uint2*)(kb_s + byte) = make_uint2(pk2(s0, s1), pk2(s2, s3));
        atomicAdd(&sqn_s[key], 0.5f * (s0 * s0 + s1 * s1 + s2 * s2 + s3 * s3));
        float4 fv = *(const float4*)(vg + base + (size_t)key * DD + d0);
        float vv[4] = {fv.x, fv.y, fv.z, fv.w};
#pragma unroll
        for (int e = 0; e < 4; ++e) {
            int dd = d0 + e;
            int vb = (dd << 7) + (key << 1); vb ^= (dd & 7) << 4;
            *(unsigned short*)(vt_s + vb) = f2bf(vv[e]);
        }
    }
    __syncthreads();

    const int lane = tid & 63;
    const int wv = tid >> 6;
    const int c = lane & 15;
    const int g = lane >> 4;
    const int fb = wv * 16;

    // projT-as-B: lane reads proj row (fb+c), dims 32kt+8g..+8 (contiguous)
    const float* prow = pg + (size_t)(fb + c) * DD;
    short8 pjb[2];
#pragma unroll
    for (int kt = 0; kt < 2; ++kt) {
        int d0 = kt * 32 + g * 8;
        float4 f0 = *(const float4*)(prow + d0);
        float4 f1 = *(const float4*)(prow + d0 + 4);
        union { unsigned u[4]; short8 s; } r;
        r.u[0] = pk2(f0.x, f0.y); r.u[1] = pk2(f0.z, f0.w);
        r.u[2] = pk2(f1.x, f1.y); r.u[3] = pk2(f1.z, f1.w);
        pjb[kt] = r.s;
    }

    // phi_k C-frags [w][f]: 4 w-tiles
    f32x4 pc[4];
    float zp = 0.f;
#pragma unroll
    for (int t = 0; t < 4; ++t) {
        f32x4 s = {0.f, 0.f, 0.f, 0.f};
        short8 ka0 = ldsfrag(kb_s, t * 16 + c, 7, g * 16);
        short8 ka1 = ldsfrag(kb_s, t * 16 + c, 7, g * 16 + 64);
        s = mfma16(ka0, pjb[0], s);
        s = mfma16(ka1, pjb[1], s);
#pragma unroll
        for (int r = 0; r < 4; ++r) {
            int w = t * 16 + g * 4 + r;
            float lg = fminf(fmaxf(s[r] - sqn_s[w], -20.f), 20.f);
            float p = __expf(lg) * 0.125f;
            s[r] = p;
            zp += p;
        }
        pc[t] = s;
    }
    zp += __shfl_xor(zp, 16);
    zp += __shfl_xor(zp, 32);
    if (lane < 16) zg[(size_t)bid * 64 + fb + c] = zp;

    short8 pb0 = xform(pc[0], pc[1], lane);
    short8 pb1 = xform(pc[2], pc[3], lane);

    float* Sout = Sg + (size_t)bid * 4096;   // [d][f]
#pragma unroll
    for (int dt = 0; dt < 4; ++dt) {
        f32x4 s = {0.f, 0.f, 0.f, 0.f};
        short8 v0 = ldsfrag(vt_s, dt * 16 + c, 7, g * 16);
        short8 v1 = ldsfrag(vt_s, dt * 16 + c, 7, g * 16 + 64);
        s = mfma16(v0, pb0, s);
        s = mfma16(v1, pb1, s);
#pragma unroll
        for (int r = 0; r < 4; ++r)
            Sout[(size_t)(dt * 16 + g * 4 + r) * 64 + fb + c] = s[r];
    }
}

// ---------------------------------------------------------------------------
// Kernel 2: shifted prefix sum over blocks (delay 2), unchanged (layout-agnostic)
// ---------------------------------------------------------------------------
__global__ __launch_bounds__(256) void k_scan(float* __restrict__ S,
                                              float* __restrict__ z) {
    const int tid = threadIdx.x;
    if (blockIdx.x < 256) {
        int pair = blockIdx.x >> 4;
        int chunk = blockIdx.x & 15;
        int elem = chunk * 256 + tid;
        size_t base = (size_t)pair * NBLK * FF * DD + elem;
        const size_t stride = FF * DD;
        float c0 = 0.f, c1 = 0.f;
        for (int n = 0; n < NBLK; ++n) {
            size_t idx = base + (size_t)n * stride;
            float val = S[idx];
            S[idx] = c0;
            c0 = c1;
            c1 += val;
        }
    } else {
        int i = (blockIdx.x - 256) * 256 + tid;
        int pair = i >> 6;
        int f = i & 63;
        size_t base = (size_t)pair * NBLK * FF + f;
        float c0 = 0.f, c1 = 0.f;
        for (int n = 0; n < NBLK; ++n) {
            size_t idx = base + (size_t)n * FF;
            float val = z[idx];
            z[idx] = c0;
            c0 = c1;
            c1 += val;
        }
    }
}

// ---------------------------------------------------------------------------
// Main: per (b,h,n), 256 threads = 4 waves, wave w = query rows 16w..16w+15.
// scores^T = kk2·q^T ; out^T = [v^T | S^T]·[a^T | phi^T], all MFMA.
// ---------------------------------------------------------------------------
__global__ __launch_bounds__(256, 3) void k_main(const float* __restrict__ qg,
                                                 const float* __restrict__ kg,
                                                 const float* __restrict__ vg,
                                                 const float* __restrict__ pg,
                                                 const float* __restrict__ Sg,
                                                 const float* __restrict__ zg,
                                                 float* __restrict__ outg) {
    __shared__ __align__(16) char k2_s[128 * 128];  // [key 0..127][64 bf16] swz, k*SCL
    __shared__ __align__(16) char vt_s[64 * 256];   // [d][128 keys bf16] swz
    __shared__ __align__(16) char pj_s[64 * 128];   // [f][64 bf16] swz
    __shared__ __align__(16) char st_s[64 * 128];   // [d][64 f bf16] swz
    __shared__ float z_s[64];

    const int tid = threadIdx.x;
    const int bid = blockIdx.x;
    const int n = bid & 63;
    const int h = (bid >> 6) & 31;
    const int b = bid >> 11;
    const int kv = h >> 2;
    const int sblk = ((b * HKV + kv) << 6) + n;
    const size_t kvbase = ((size_t)(b * HKV + kv) * TT + (size_t)n * WW) * DD;
    const size_t qrow0 = (size_t)(b * HH + h) * TT + (size_t)n * WW;

    // ---- stage
    const float4* p4 = (const float4*)pg;
    const float4* S4 = (const float4*)(Sg + (size_t)sblk * 4096);
    for (int j = 0; j < 8; ++j) {
        int i4 = tid + j * 256;          // 0..2047
        int key = i4 >> 4;               // 0..127 (0..63 = prev block)
        int d0 = (i4 & 15) << 2;
        if (n > 0 || key >= 64) {
            const float* src = kg + kvbase + (long)(key - 64) * DD + d0;
            float4 f = *(const float4*)src;
            int byte = (key << 7) + (d0 << 1); byte ^= (key & 7) << 4;
            *(uint2*)(k2_s + byte) =
                make_uint2(pk2(f.x * SCL, f.y * SCL), pk2(f.z * SCL, f.w * SCL));
        }
        {
            float4 f;
            if (n > 0 || key >= 64)
                f = *(const float4*)(vg + kvbase + (long)(key - 64) * DD + d0);
            else
                f = make_float4(0.f, 0.f, 0.f, 0.f);   // must be 0: a=0 * NaN guard
            float vv[4] = {f.x, f.y, f.z, f.w};
#pragma unroll
            for (int e = 0; e < 4; ++e) {
                int dd = d0 + e;
                int byte = (dd << 8) + (key << 1); byte ^= (dd & 7) << 4;
                *(unsigned short*)(vt_s + byte) = f2bf(vv[e]);
            }
        }
        if (j < 4) {
            int row = i4 >> 4;           // 0..63
            float4 fp = p4[i4];
            int byte = (row << 7) + (d0 << 1); byte ^= (row & 7) << 4;
            *(uint2*)(pj_s + byte) = make_uint2(pk2(fp.x, fp.y), pk2(fp.z, fp.w));
            float4 fs = S4[i4];
            *(uint2*)(st_s + byte) = make_uint2(pk2(fs.x, fs.y), pk2(fs.z, fs.w));
        }
    }
    if (tid < 64) z_s[tid] = zg[(size_t)sblk * 64 + tid];
    __syncthreads();

    const int lane = tid & 63;
    const int w = tid >> 6;
    const int c = lane & 15;
    const int g = lane >> 4;
    const int qr = (w << 4) + c;     // query row in block (this lane's column)

    // ---- q as B-frags (from global) + sqn
    const float* qrow = qg + (qrow0 + qr) * DD;
    float sq = 0.f;
    short8 qb[2];
#pragma unroll
    for (int kt = 0; kt < 2; ++kt) {
        int d0 = kt * 32 + g * 8;
        float4 f0 = *(const float4*)(qrow + d0);
        float4 f1 = *(const float4*)(qrow + d0 + 4);
        float s0 = f0.x * SCL, s1 = f0.y * SCL, s2 = f0.z * SCL, s3 = f0.w * SCL;
        float s4 = f1.x * SCL, s5 = f1.y * SCL, s6 = f1.z * SCL, s7 = f1.w * SCL;
        sq += s0 * s0 + s1 * s1 + s2 * s2 + s3 * s3 + s4 * s4 + s5 * s5 + s6 * s6 + s7 * s7;
        union { unsigned u[4]; short8 s; } r;
        r.u[0] = pk2(s0, s1); r.u[1] = pk2(s2, s3);
        r.u[2] = pk2(s4, s5); r.u[3] = pk2(s6, s7);
        qb[kt] = r.s;
    }
    sq += __shfl_xor(sq, 16);
    sq += __shfl_xor(sq, 32);
    const float sqn = 0.5f * sq;

    // ---- scores^T (8 key-tiles), masked exp, asum
    float ar[8][4];
    float asum = 0.f;
#pragma unroll
    for (int t = 0; t < 8; ++t) {
        f32x4 sc = {0.f, 0.f, 0.f, 0.f};
        short8 ka0 = ldsfrag(k2_s, t * 16 + c, 7, g * 16);
        short8 ka1 = ldsfrag(k2_s, t * 16 + c, 7, g * 16 + 64);
        sc = mfma16(ka0, qb[0], sc);
        sc = mfma16(ka1, qb[1], sc);
#pragma unroll
        for (int r = 0; r < 4; ++r) {
            int key = t * 16 + g * 4 + r;
            bool valid = (key >= 64) ? ((key - 64) <= qr) : (n > 0);
            float a = 0.f;
            if (valid) a = __expf(fminf(fmaxf(sc[r], -30.f), 30.f));
            ar[t][r] = a;
            asum += a;
        }
    }
    asum += __shfl_xor(asum, 16);
    asum += __shfl_xor(asum, 32);

    // ---- a^T C-frags -> B-frags for num_loc^T
    short8 ab[4];
#pragma unroll
    for (int kt = 0; kt < 4; ++kt) {
        f32x4 t0, t1;
#pragma unroll
        for (int r = 0; r < 4; ++r) { t0[r] = ar[2 * kt][r]; t1[r] = ar[2 * kt + 1][r]; }
        ab[kt] = xform(t0, t1, lane);
    }

    // ---- phi_q^T (4 f-tiles) + den_lin
    float dl = 0.f;
    f32x4 ph[4];
#pragma unroll
    for (int ft = 0; ft < 4; ++ft) {
        f32x4 pf = {0.f, 0.f, 0.f, 0.f};
        short8 pa0 = ldsfrag(pj_s, ft * 16 + c, 7, g * 16);
        short8 pa1 = ldsfrag(pj_s, ft * 16 + c, 7, g * 16 + 64);
        pf = mfma16(pa0, qb[0], pf);
        pf = mfma16(pa1, qb[1], pf);
#pragma unroll
        for (int r = 0; r < 4; ++r) {
            float lg = fminf(fmaxf(pf[r] - sqn, -20.f), 20.f);
            float p = __expf(lg) * 0.125f;
            pf[r] = p;
            dl += p * z_s[ft * 16 + g * 4 + r];
        }
        ph[ft] = pf;
    }
    dl += __shfl_xor(dl, 16);
    dl += __shfl_xor(dl, 32);

    short8 pb[2];
    pb[0] = xform(ph[0], ph[1], lane);
    pb[1] = xform(ph[2], ph[3], lane);

    // ---- out^T = v^T·a^T + S^T·phi^T  (accumulate in one C set)
    f32x4 acc[4];
#pragma unroll
    for (int dt = 0; dt < 4; ++dt) {
        f32x4 a4 = {0.f, 0.f, 0.f, 0.f};
#pragma unroll
        for (int kt = 0; kt < 4; ++kt) {
            short8 vf = ldsfrag(vt_s, dt * 16 + c, 8, g * 16 + kt * 64);
            a4 = mfma16(vf, ab[kt], a4);
        }
        short8 s0 = ldsfrag(st_s, dt * 16 + c, 7, g * 16);
        short8 s1 = ldsfrag(st_s, dt * 16 + c, 7, g * 16 + 64);
        a4 = mfma16(s0, pb[0], a4);
        a4 = mfma16(s1, pb[1], a4);
        acc[dt] = a4;
    }

    const float inv = 1.f / (asum + dl + 1e-6f);
    float* orow = outg + (qrow0 + qr) * DD;
#pragma unroll
    for (int dt = 0; dt < 4; ++dt)
#pragma unroll
        for (int r = 0; r < 4; ++r)
            orow[dt * 16 + g * 4 + r] = acc[dt][r] * inv;
}

// ---------------------------------------------------------------------------
extern "C" void kernel_launch(void* const* d_in, const int* in_sizes, int n_in,
                              void* d_out, int out_size, void* d_ws, size_t ws_size,
                              hipStream_t stream) {
    const float* q = (const float*)d_in[0];
    const float* k = (const float*)d_in[1];
    const float* v = (const float*)d_in[2];
    const float* proj = (const float*)d_in[3];
    float* out = (float*)d_out;

    float* S = (float*)d_ws;                                  // [B*HKV*NB][D][F]
    float* z = S + (size_t)BB * HKV * NBLK * FF * DD;         // [B*HKV*NB][F]

    k_phase1<<<dim3(BB * HKV * NBLK), dim3(256), 0, stream>>>(k, v, proj, S, z);
    k_scan<<<dim3(260), dim3(256), 0, stream>>>(S, z);
    k_main<<<dim3(BB * HH * NBLK), dim3(256), 0, stream>>>(q, k, v, proj, S, z, out);
}